// Round 1
// baseline (983.768 us; speedup 1.0000x reference)
//
#include <hip/hip_runtime.h>
#include <math.h>

#define BB 2
#define SS 2048
#define DD 1024
#define HH 16
#define DKK 64
#define NTOK (BB*SS)            // 4096
#define ND ((size_t)NTOK*(size_t)DD)   // 4194304

typedef __attribute__((ext_vector_type(8))) short bf16x8;
typedef __attribute__((ext_vector_type(4))) float f32x4;

__device__ __forceinline__ unsigned short f2bf(float f) {
  union { float f; unsigned u; } c; c.f = f;
  unsigned u = c.u;
  unsigned r = u + 0x7fffu + ((u >> 16) & 1u);
  return (unsigned short)(r >> 16);
}
__device__ __forceinline__ float bf2f(unsigned short h) {
  union { unsigned u; float f; } c; c.u = ((unsigned)h) << 16;
  return c.f;
}

// ---------------- convert all fp32 inputs to bf16 (contiguous dst) ----------
__global__ void k_cvt_all(const float* __restrict__ s0, const float* __restrict__ s1,
                          const float* __restrict__ s2, const float* __restrict__ s3,
                          const float* __restrict__ s4, const float* __restrict__ s5,
                          const float* __restrict__ s6, unsigned short* __restrict__ dst)
{
  size_t i4 = ((size_t)blockIdx.x * blockDim.x + threadIdx.x) * 4;
  const float* src; size_t off;
  if      (i4 <  4194304) { src = s0; off = 0; }
  else if (i4 <  8388608) { src = s1; off = 4194304; }
  else if (i4 < 12582912) { src = s2; off = 8388608; }
  else if (i4 < 13631488) { src = s3; off = 12582912; }
  else if (i4 < 14680064) { src = s4; off = 13631488; }
  else if (i4 < 15728640) { src = s5; off = 14680064; }
  else                    { src = s6; off = 15728640; }
  float4 v = *(const float4*)(src + (i4 - off));
  ushort4 o; o.x = f2bf(v.x); o.y = f2bf(v.y); o.z = f2bf(v.z); o.w = f2bf(v.w);
  *(ushort4*)(dst + i4) = o;
}

// ---------------- RoPE tables (base 4500 for S=2048) ------------------------
__global__ void k_rope_table(float* __restrict__ cosT, float* __restrict__ sinT) {
  int idx = blockIdx.x * blockDim.x + threadIdx.x;   // SS*32
  int s = idx >> 5, i = idx & 31;
  float theta = (float)pow(4500.0, -(double)i / 16.0);
  float ang = (float)s * theta;                       // fp32-rounded angle like np
  double a = (double)ang;
  cosT[idx] = (float)cos(a);
  sinT[idx] = (float)sin(a);
}

// ---------------- in-place RoPE on bf16 q/k; q scaled by 1/8 ----------------
__global__ void k_rope_apply(unsigned short* __restrict__ q, unsigned short* __restrict__ k,
                             const float* __restrict__ cosT, const float* __restrict__ sinT) {
  int idx = blockIdx.x * blockDim.x + threadIdx.x;   // BB*SS*HH*32 = 2097152
  int tensor = blockIdx.y;                            // 0=q,1=k
  int i = idx & 31;
  int h = (idx >> 5) & 15;
  int s = (idx >> 9) & 2047;
  int b = idx >> 20;
  size_t off = ((size_t)(b * SS + s)) * DD + h * DKK + 2 * i;
  unsigned short* p = tensor ? k : q;
  float c = cosT[(s << 5) | i], sn = sinT[(s << 5) | i];
  unsigned v32 = *(const unsigned*)(p + off);
  float xe = bf2f((unsigned short)(v32 & 0xffffu));
  float xo = bf2f((unsigned short)(v32 >> 16));
  float re = xe * c - xo * sn;
  float ro = xe * sn + xo * c;
  if (tensor == 0) { re *= 0.125f; ro *= 0.125f; }    // fold 1/sqrt(DK) into q
  *(unsigned*)(p + off) = (unsigned)f2bf(re) | ((unsigned)f2bf(ro) << 16);
}

// ---------------- V transpose: (B,S,D) bf16 -> (B,H,DK,S) bf16 --------------
__global__ void k_transpose_v(const unsigned short* __restrict__ vb, unsigned short* __restrict__ vt) {
  __shared__ unsigned short tile[64][66];
  int st = blockIdx.x * 64;
  int bh = blockIdx.y;
  int b = bh >> 4, h = bh & 15;
  int t = threadIdx.x;
  for (int i = 0; i < 16; ++i) {
    int idx = i * 256 + t;
    int r = idx >> 6, c = idx & 63;
    tile[r][c] = vb[((size_t)(b * SS + st + r)) * DD + h * DKK + c];
  }
  __syncthreads();
  for (int i = 0; i < 16; ++i) {
    int idx = i * 256 + t;
    int c = idx >> 6, r = idx & 63;
    vt[((size_t)(bh * DKK + c)) * SS + st + r] = tile[r][c];
  }
}

// ---------------- bf16 MFMA GEMM: C[M,N] = A[M,K] @ W[N,K]^T + bias ---------
__device__ __forceinline__ void gload_lds16(const unsigned short* g, unsigned short* l) {
  __builtin_amdgcn_global_load_lds((const __attribute__((address_space(1))) void*)g,
                                   (__attribute__((address_space(3))) void*)l, 16, 0, 0);
}

template<int MODE>   // 0: bf16 out, 1: fp32 out
__device__ __forceinline__ void gemm_body(const unsigned short* __restrict__ A,
                                          const unsigned short* __restrict__ W,
                                          const float* __restrict__ bias,
                                          void* __restrict__ C, int M, int N, int K)
{
  __shared__ unsigned short Asb[2][128 * 32];
  __shared__ unsigned short Bsb[2][128 * 32];
  const int tid = threadIdx.x;
  const int wave = tid >> 6, lane = tid & 63;
  const int wr = wave >> 1, wc = wave & 1;
  const int g = lane >> 4, l15 = lane & 15;
  const int rowBase = blockIdx.y * 128, colBase = blockIdx.x * 128;
  const int lrow = lane >> 2, lk = (lane & 3) * 8;

  f32x4 zf = {0.f, 0.f, 0.f, 0.f};
  f32x4 acc[4][4];
#pragma unroll
  for (int m = 0; m < 4; ++m)
#pragma unroll
    for (int n = 0; n < 4; ++n) acc[m][n] = zf;

  auto stage = [&](int buf, int kt) {
    const unsigned short* Ag = A + (size_t)rowBase * K + kt * 32;
    const unsigned short* Bg = W + (size_t)colBase * K + kt * 32;
#pragma unroll
    for (int ii = 0; ii < 2; ++ii) {
      int i = wave + ii * 4;
      gload_lds16(Ag + (size_t)(16 * i + lrow) * K + lk, &Asb[buf][i * 512]);
      gload_lds16(Bg + (size_t)(16 * i + lrow) * K + lk, &Bsb[buf][i * 512]);
    }
  };

  const int nk = K >> 5;
  stage(0, 0);
  for (int kt = 0; kt < nk; ++kt) {
    __syncthreads();
    if (kt + 1 < nk) stage((kt + 1) & 1, kt + 1);
    const unsigned short* As = Asb[kt & 1];
    const unsigned short* Bs = Bsb[kt & 1];
    bf16x8 af[4], bfr[4];
#pragma unroll
    for (int m = 0; m < 4; ++m)
      af[m] = *(const bf16x8*)(As + (wr * 64 + 16 * m + l15) * 32 + g * 8);
#pragma unroll
    for (int n = 0; n < 4; ++n)
      bfr[n] = *(const bf16x8*)(Bs + (wc * 64 + 16 * n + l15) * 32 + g * 8);
#pragma unroll
    for (int m = 0; m < 4; ++m)
#pragma unroll
      for (int n = 0; n < 4; ++n)
        acc[m][n] = __builtin_amdgcn_mfma_f32_16x16x32_bf16(af[m], bfr[n], acc[m][n], 0, 0, 0);
  }

  float bvv[4];
#pragma unroll
  for (int n = 0; n < 4; ++n) bvv[n] = bias[colBase + wc * 64 + 16 * n + l15];
#pragma unroll
  for (int m = 0; m < 4; ++m)
#pragma unroll
    for (int n = 0; n < 4; ++n)
#pragma unroll
      for (int r = 0; r < 4; ++r) {
        int row = rowBase + wr * 64 + 16 * m + g * 4 + r;
        int col = colBase + wc * 64 + 16 * n + l15;
        float v = acc[m][n][r] + bvv[n];
        if (MODE == 0) ((unsigned short*)C)[(size_t)row * N + col] = f2bf(v);
        else           ((float*)C)[(size_t)row * N + col] = v;
      }
}

__global__ __launch_bounds__(256) void k_gemm_qkv(
    const unsigned short* __restrict__ Xq, const unsigned short* __restrict__ Xk, const unsigned short* __restrict__ Xv,
    const unsigned short* __restrict__ Wqb, const unsigned short* __restrict__ Wkb, const unsigned short* __restrict__ Wvb,
    const float* __restrict__ bq, const float* __restrict__ bk, const float* __restrict__ bv,
    unsigned short* __restrict__ dq, unsigned short* __restrict__ dk, unsigned short* __restrict__ dv)
{
  int z = blockIdx.z;
  const unsigned short* A = (z == 0) ? Xq : (z == 1) ? Xk : Xv;
  const unsigned short* W = (z == 0) ? Wqb : (z == 1) ? Wkb : Wvb;
  const float* bi = (z == 0) ? bq : (z == 1) ? bk : bv;
  unsigned short* C = (z == 0) ? dq : (z == 1) ? dk : dv;
  gemm_body<0>(A, W, bi, C, NTOK, DD, DD);
}

__global__ __launch_bounds__(256) void k_gemm_out(
    const unsigned short* __restrict__ A, const unsigned short* __restrict__ W,
    const float* __restrict__ bias, float* __restrict__ C)
{
  gemm_body<1>(A, W, bias, C, NTOK, DD, DD);
}

// ---------------- single-pass attention -------------------------------------
// block = 8 waves, handles (b,h, 32 q-rows); wave w owns keys [w*256,(w+1)*256)
__global__ __launch_bounds__(512) void k_attn(
    const unsigned short* __restrict__ qb,   // (B,S,D) roped, q pre-scaled 1/8
    const unsigned short* __restrict__ kb,   // (B,S,D) roped
    const unsigned short* __restrict__ vt,   // (B,H,DK,S)
    float* __restrict__ attn,                // (B,H,S,S) fp32
    unsigned short* __restrict__ ctx)        // (B,S,D) bf16
{
  __shared__ unsigned short pbuf[8][32 * 32];
  __shared__ float s_m[8][32];
  __shared__ float s_l[8][32];
  __shared__ float cbuf[32][64];

  const int blk = blockIdx.x;
  const int qt = blk & 63;
  const int bh = blk >> 6;
  const int b = bh >> 4, h = bh & 15;
  const int tid = threadIdx.x;
  const int wave = tid >> 6, lane = tid & 63;
  const int g = lane >> 4, l15 = lane & 15;
  const int q0 = qt * 32;

  // zero ctx reduction buffer (before first barrier)
  {
    float* cz = &cbuf[0][0];
    for (int i = tid; i < 32 * 64; i += 512) cz[i] = 0.f;
  }

  // Q fragments (A operand): row = l15 (+16m), k = kk*32 + g*8 + j
  const unsigned short* qbase = qb + ((size_t)(b * SS + q0)) * DD + h * DKK;
  bf16x8 aq[2][2];
#pragma unroll
  for (int m = 0; m < 2; ++m)
#pragma unroll
    for (int kk = 0; kk < 2; ++kk)
      aq[m][kk] = *(const bf16x8*)(qbase + (size_t)(16 * m + l15) * DD + kk * 32 + g * 8);

  f32x4 zf = {0.f, 0.f, 0.f, 0.f};
  f32x4 acc[2][16];
#pragma unroll
  for (int m = 0; m < 2; ++m)
#pragma unroll
    for (int n = 0; n < 16; ++n) acc[m][n] = zf;

  // QK^T over this wave's 256-key slice
  const unsigned short* kbase = kb + ((size_t)(b * SS + wave * 256)) * DD + h * DKK;
#pragma unroll
  for (int n = 0; n < 16; ++n) {
    bf16x8 bk0 = *(const bf16x8*)(kbase + (size_t)(n * 16 + l15) * DD + g * 8);
    bf16x8 bk1 = *(const bf16x8*)(kbase + (size_t)(n * 16 + l15) * DD + 32 + g * 8);
#pragma unroll
    for (int m = 0; m < 2; ++m) {
      acc[m][n] = __builtin_amdgcn_mfma_f32_16x16x32_bf16(aq[m][0], bk0, acc[m][n], 0, 0, 0);
      acc[m][n] = __builtin_amdgcn_mfma_f32_16x16x32_bf16(aq[m][1], bk1, acc[m][n], 0, 0, 0);
    }
  }

  // wave-local row max (row = 16m + 4g + r, 16 lanes per row)
  float lm[2][4];
#pragma unroll
  for (int m = 0; m < 2; ++m)
#pragma unroll
    for (int r = 0; r < 4; ++r) {
      float mx = acc[m][0][r];
#pragma unroll
      for (int n = 1; n < 16; ++n) mx = fmaxf(mx, acc[m][n][r]);
      mx = fmaxf(mx, __shfl_xor(mx, 1));
      mx = fmaxf(mx, __shfl_xor(mx, 2));
      mx = fmaxf(mx, __shfl_xor(mx, 4));
      mx = fmaxf(mx, __shfl_xor(mx, 8));
      lm[m][r] = mx;
    }
  if (l15 == 0) {
#pragma unroll
    for (int m = 0; m < 2; ++m)
#pragma unroll
      for (int r = 0; r < 4; ++r) s_m[wave][16 * m + 4 * g + r] = lm[m][r];
  }
  __syncthreads();

  // global max, exp, wave-local sums
  float gm[2][4];
#pragma unroll
  for (int m = 0; m < 2; ++m)
#pragma unroll
    for (int r = 0; r < 4; ++r) {
      int row = 16 * m + 4 * g + r;
      float mx = s_m[0][row];
#pragma unroll
      for (int w = 1; w < 8; ++w) mx = fmaxf(mx, s_m[w][row]);
      gm[m][r] = mx;
    }
  float lsum[2][4];
#pragma unroll
  for (int m = 0; m < 2; ++m)
#pragma unroll
    for (int r = 0; r < 4; ++r) {
      float sm = 0.f;
#pragma unroll
      for (int n = 0; n < 16; ++n) {
        float p = __expf(acc[m][n][r] - gm[m][r]);
        acc[m][n][r] = p;
        sm += p;
      }
      sm += __shfl_xor(sm, 1);
      sm += __shfl_xor(sm, 2);
      sm += __shfl_xor(sm, 4);
      sm += __shfl_xor(sm, 8);
      lsum[m][r] = sm;
    }
  if (l15 == 0) {
#pragma unroll
    for (int m = 0; m < 2; ++m)
#pragma unroll
      for (int r = 0; r < 4; ++r) s_l[wave][16 * m + 4 * g + r] = lsum[m][r];
  }
  __syncthreads();

  float rln[2][4];
#pragma unroll
  for (int m = 0; m < 2; ++m)
#pragma unroll
    for (int r = 0; r < 4; ++r) {
      int row = 16 * m + 4 * g + r;
      float sum = s_l[0][row];
#pragma unroll
      for (int w = 1; w < 8; ++w) sum += s_l[w][row];
      rln[m][r] = 1.f / sum;
    }

  // normalize + write attn (fp32)
  float* arow = attn + ((size_t)(bh * SS + q0)) * SS + wave * 256;
#pragma unroll
  for (int m = 0; m < 2; ++m)
#pragma unroll
    for (int r = 0; r < 4; ++r) {
      int row = 16 * m + 4 * g + r;
      float sc = rln[m][r];
#pragma unroll
      for (int n = 0; n < 16; ++n) {
        float p = acc[m][n][r] * sc;
        acc[m][n][r] = p;
        arow[(size_t)row * SS + n * 16 + l15] = p;
      }
    }

  // PV: ctx_partial[32 x 64] over this wave's keys, P via per-wave LDS bounce
  f32x4 cacc[2][4];
#pragma unroll
  for (int m = 0; m < 2; ++m)
#pragma unroll
    for (int n = 0; n < 4; ++n) cacc[m][n] = zf;

  unsigned short* pb = pbuf[wave];
  const unsigned short* vbase = vt + ((size_t)(bh * DKK)) * SS + wave * 256;
#pragma unroll
  for (int c = 0; c < 8; ++c) {
#pragma unroll
    for (int m = 0; m < 2; ++m)
#pragma unroll
      for (int nn = 0; nn < 2; ++nn)
#pragma unroll
        for (int r = 0; r < 4; ++r) {
          int row = 16 * m + 4 * g + r;
          pb[row * 32 + nn * 16 + l15] = f2bf(acc[m][2 * c + nn][r]);
        }
    bf16x8 pa[2];
#pragma unroll
    for (int m = 0; m < 2; ++m)
      pa[m] = *(const bf16x8*)(pb + (16 * m + l15) * 32 + g * 8);
#pragma unroll
    for (int n = 0; n < 4; ++n) {
      bf16x8 bv = *(const bf16x8*)(vbase + (size_t)(16 * n + l15) * SS + c * 32 + g * 8);
#pragma unroll
      for (int m = 0; m < 2; ++m)
        cacc[m][n] = __builtin_amdgcn_mfma_f32_16x16x32_bf16(pa[m], bv, cacc[m][n], 0, 0, 0);
    }
  }

  // reduce ctx across waves
#pragma unroll
  for (int m = 0; m < 2; ++m)
#pragma unroll
    for (int n = 0; n < 4; ++n)
#pragma unroll
      for (int r = 0; r < 4; ++r)
        atomicAdd(&cbuf[16 * m + 4 * g + r][16 * n + l15], cacc[m][n][r]);
  __syncthreads();

  {
    int row = tid >> 4;
    int d0 = (tid & 15) * 4;
    ushort4 o;
    o.x = f2bf(cbuf[row][d0 + 0]);
    o.y = f2bf(cbuf[row][d0 + 1]);
    o.z = f2bf(cbuf[row][d0 + 2]);
    o.w = f2bf(cbuf[row][d0 + 3]);
    *(ushort4*)(ctx + ((size_t)(b * SS + q0 + row)) * DD + h * DKK + d0) = o;
  }
}

// ---------------- host launch ------------------------------------------------
extern "C" void kernel_launch(void* const* d_in, const int* in_sizes, int n_in,
                              void* d_out, int out_size, void* d_ws, size_t ws_size,
                              hipStream_t stream)
{
  (void)in_sizes; (void)n_in; (void)out_size; (void)ws_size;
  const float* q_in = (const float*)d_in[0];
  const float* k_in = (const float*)d_in[1];
  const float* v_in = (const float*)d_in[2];
  const float* Wq = (const float*)d_in[3];
  const float* bq = (const float*)d_in[4];
  const float* Wk = (const float*)d_in[5];
  const float* bk = (const float*)d_in[6];
  const float* Wv = (const float*)d_in[7];
  const float* bv = (const float*)d_in[8];
  const float* Wo = (const float*)d_in[9];
  const float* bo = (const float*)d_in[10];

  float* out = (float*)d_out;
  float* attn = out + ND;

  unsigned short* us = (unsigned short*)d_ws;
  unsigned short* Xq  = us + 0;
  unsigned short* Xk  = us + 4194304;
  unsigned short* Xv  = us + 8388608;
  unsigned short* Wqb = us + 12582912;
  unsigned short* Wkb = us + 13631488;
  unsigned short* Wvb = us + 14680064;
  unsigned short* Wob = us + 15728640;
  unsigned short* qb  = us + 16777216;
  unsigned short* kb  = us + 20971520;
  unsigned short* vb  = us + 25165824;
  unsigned short* vt  = us + 29360128;
  unsigned short* ctx = us + 33554432;
  float* cosT = (float*)(us + 37748736);
  float* sinT = cosT + SS * 32;

  k_cvt_all<<<16384, 256, 0, stream>>>(q_in, k_in, v_in, Wq, Wk, Wv, Wo, us);
  k_rope_table<<<256, 256, 0, stream>>>(cosT, sinT);
  k_gemm_qkv<<<dim3(DD / 128, NTOK / 128, 3), 256, 0, stream>>>(
      Xq, Xk, Xv, Wqb, Wkb, Wvb, bq, bk, bv, qb, kb, vb);
  k_rope_apply<<<dim3(8192, 2), 256, 0, stream>>>(qb, kb, cosT, sinT);
  k_transpose_v<<<dim3(SS / 64, BB * HH), 256, 0, stream>>>(vb, vt);
  k_attn<<<BB * HH * (SS / 32), 512, 0, stream>>>(qb, kb, vt, attn, ctx);
  k_gemm_out<<<dim3(DD / 128, NTOK / 128), 256, 0, stream>>>(ctx, Wob, bo, out);
}